// Round 12
// baseline (593.329 us; speedup 1.0000x reference)
//
#include <hip/hip_runtime.h>
#include <cstdint>
#include <cstddef>

typedef __attribute__((ext_vector_type(8))) short short8;
typedef __attribute__((ext_vector_type(4))) short short4v;
typedef __attribute__((ext_vector_type(4))) float float4v;

#define DEV static __device__ __forceinline__

DEV float b2f(unsigned short u) { return __uint_as_float(((unsigned int)u) << 16); }
DEV unsigned short f2b(float f) {
  unsigned int u = __float_as_uint(f);
  u = (u + 0x7fffu + ((u >> 16) & 1u)) >> 16;
  return (unsigned short)u;
}

#define MFMA32(a, b, c) __builtin_amdgcn_mfma_f32_16x16x32_bf16(a, b, c, 0, 0, 0)

// ---- problem sizes ----
static constexpr int NP   = 12416;  // qkvz stride: 8192 qkv + 4096 z + 32 a + 32 b + 64 pad
static constexpr int NPAD = 12544;  // wcat rows padded to 49*256 for 256-col B tiles

// ---- ws layout (bytes), lifetime-overlaid; peak ~162 MB ----
static constexpr size_t OFF_QKVZ = 0;
static constexpr size_t SZ_QKVZ  = (size_t)4096*NP*2;        // 101,711,872
static constexpr size_t OFF_XB   = SZ_QKVZ;
static constexpr size_t SZ_XB    = (size_t)4096*2048*2;      // 16,777,216
static constexpr size_t OFF_WCAT = OFF_XB + SZ_XB;
static constexpr size_t SZ_WCAT  = (size_t)NPAD*2048*2;      // 51,380,224
static constexpr size_t OFF_QKVS = OFF_XB;                   // overlays xb+wcat after GEMM1
static constexpr size_t SZ_QKVS  = (size_t)4096*8192*2;      // 67,108,864
static constexpr size_t OFF_G    = OFF_XB + SZ_QKVS;         // fits in gap before wcat end
static constexpr size_t OFF_BET  = OFF_G + (size_t)4096*32*4;
static constexpr size_t OFF_YN   = OFF_XB;                   // after scan
static constexpr size_t SZ_YN    = (size_t)4096*4096*2;
static constexpr size_t OFF_WOB  = OFF_YN + SZ_YN;
static constexpr size_t WS_NEED  = OFF_WCAT + SZ_WCAT;       // 169,869,312

// ---- helpers ----
DEV void gl16(const unsigned short* g, char* l) {
  __builtin_amdgcn_global_load_lds((const __attribute__((address_space(1))) unsigned int*)g,
                                   (__attribute__((address_space(3))) unsigned int*)l,
                                   16, 0, 0);
}

DEV void store_out(unsigned short* C, size_t off, float v) { C[off] = f2b(v); }
DEV void store_out(float* C, size_t off, float v)          { C[off] = v; }

// ---- generic cast fp32 -> bf16 (n multiple of 4) ----
__global__ void castk(const float* __restrict__ in, unsigned short* __restrict__ out, int n4) {
  int idx = blockIdx.x * 256 + threadIdx.x;
  if (idx >= n4) return;
  float4v v = ((const float4v*)in)[idx];
  short4v o;
  o[0] = (short)f2b(v[0]); o[1] = (short)f2b(v[1]);
  o[2] = (short)f2b(v[2]); o[3] = (short)f2b(v[3]);
  ((short4v*)out)[idx] = o;
}

// ---- build concatenated weight [12544][2048] bf16 ----
__global__ void prep_wcat(const float* __restrict__ Wqkv, const float* __restrict__ Wz,
                          const float* __restrict__ Wa, const float* __restrict__ Wb,
                          unsigned short* __restrict__ Wcat) {
  size_t e4 = (size_t)blockIdx.x * 256 + threadIdx.x;
  if (e4 >= (size_t)NPAD * 2048 / 4) return;
  size_t e = e4 * 4;
  int row = (int)(e >> 11);
  int col = (int)(e & 2047);
  float4v v;
  if (row < 8192)       v = *(const float4v*)&Wqkv[(size_t)row * 2048 + col];
  else if (row < 12288) v = *(const float4v*)&Wz[(size_t)(row - 8192) * 2048 + col];
  else if (row < 12320) v = *(const float4v*)&Wa[(size_t)(row - 12288) * 2048 + col];
  else if (row < 12352) v = *(const float4v*)&Wb[(size_t)(row - 12320) * 2048 + col];
  else                  v = (float4v){0.f, 0.f, 0.f, 0.f};
  short4v o;
  o[0] = (short)f2b(v[0]); o[1] = (short)f2b(v[1]);
  o[2] = (short)f2b(v[2]); o[3] = (short)f2b(v[3]);
  *(short4v*)&Wcat[e] = o;
}

// ======= 128x256 double-buffered bf16 MFMA GEMM, 2 blocks/CU =======
// C[M][NC] = A[M][K] @ B[N][K]^T. 512 thr = 8 waves (2M x 4N of 64x64), BK=32.
// acc = 64 regs/wave; __launch_bounds__(512,4) caps total regs at 128 ->
// 4 waves/SIMD = 2 blocks/CU. LDS 48 KB (2 slots of A 8KB + B 16KB).
// Cross-block wave overlap (m114) hides the per-tile vmcnt(0) drain; the
// finer block granularity cuts the 1-block/CU grid-quantization tax
// (784 tiles @1/CU = 4 fill rounds -> 1568 half-tiles @2/CU ~ 3.1 rounds).
// Swizzle: 64B rows, 16B slot s = c ^ ((row>>1)&3) (R9-verified, conflicts=0).
template <bool BNMAJOR, typename OutT>
__global__ __launch_bounds__(512, 4)
void gemm_db(const unsigned short* __restrict__ A, const unsigned short* __restrict__ B,
             OutT* __restrict__ C, int K, int nbm, int nbn, int NC) {
  constexpr int ASZ  = 128 * 64;          // 8 KB
  constexpr int SLOT = ASZ + 16384;       // 24 KB
  __shared__ __align__(16) char sm[2 * SLOT];
  const int t = threadIdx.x;
  const int cpx = gridDim.x >> 3;
  int wg = blockIdx.x;
  wg = (wg & 7) * cpx + (wg >> 3);        // bijective XCD swizzle (grid % 8 == 0)
  const int bm = BNMAJOR ? (wg % nbm) : (wg / nbn);
  const int bn = BNMAJOR ? (wg / nbm) : (wg % nbn);

  const int wv = t >> 6, lane = t & 63;
  const int l16 = lane & 15, lg = lane >> 4;
  const int wm = (wv >> 2) * 64;
  const int wn = (wv & 3) * 64;
  const int rsw = (lg ^ ((l16 >> 1) & 3)) << 4;  // swizzled 16B slot in 64B row

  size_t aoff, boff[2];
  {
    int L = t * 16;
    int row = L >> 6;
    int c = ((L >> 4) & 3) ^ ((row >> 1) & 3);
    aoff = (size_t)(bm * 128 + row) * K + (c << 3);
  }
#pragma unroll
  for (int r = 0; r < 2; r++) {
    int L = r * 8192 + t * 16;
    int row = L >> 6;
    int c = ((L >> 4) & 3) ^ ((row >> 1) & 3);
    boff[r] = (size_t)(bn * 256 + row) * K + (c << 3);
  }

  float4v acc[4][4] = {};
  const int NKT = K >> 5;

#define STAGE(J)                                                              \
  do {                                                                        \
    const size_t ko = (size_t)(J) * 32;                                       \
    char* slot = sm + ((J) & 1) * SLOT;                                       \
    gl16(A + aoff + ko, slot + t * 16);                                       \
    gl16(B + boff[0] + ko, slot + ASZ + t * 16);                              \
    gl16(B + boff[1] + ko, slot + ASZ + 8192 + t * 16);                       \
  } while (0)

  // prologue
  STAGE(0);
  asm volatile("s_waitcnt vmcnt(0)" ::: "memory");
  __builtin_amdgcn_s_barrier();

  for (int j = 0; j < NKT; j++) {
    char* ab = sm + (j & 1) * SLOT;
    char* bb = ab + ASZ;
    if (j + 1 < NKT) STAGE(j + 1);
    short8 av[4], bv[4];
#pragma unroll
    for (int mi = 0; mi < 4; mi++)
      av[mi] = *(const short8*)(ab + (wm + mi * 16 + l16) * 64 + rsw);
#pragma unroll
    for (int nn = 0; nn < 4; nn++)
      bv[nn] = *(const short8*)(bb + (wn + nn * 16 + l16) * 64 + rsw);
    __builtin_amdgcn_s_setprio(1);
#pragma unroll
    for (int mi = 0; mi < 4; mi++)
#pragma unroll
      for (int nn = 0; nn < 4; nn++)
        acc[mi][nn] = MFMA32(av[mi], bv[nn], acc[mi][nn]);
    __builtin_amdgcn_s_setprio(0);
    asm volatile("s_waitcnt vmcnt(0)" ::: "memory");
    __builtin_amdgcn_s_barrier();
  }
#undef STAGE

  // epilogue
#pragma unroll
  for (int mi = 0; mi < 4; mi++) {
    int row0 = bm * 128 + wm + mi * 16 + lg * 4;
#pragma unroll
    for (int nn = 0; nn < 4; nn++) {
      int col = bn * 256 + wn + nn * 16 + l16;
      if (col < NC) {
#pragma unroll
        for (int rr = 0; rr < 4; rr++)
          store_out(C, (size_t)(row0 + rr) * NC + col, acc[mi][nn][rr]);
      }
    }
  }
}

// ---- conv(KW=4) + silu + q/k L2-norm, time-chunked (halo L1-reuse) ----
__global__ __launch_bounds__(1024)
void conv_silu_norm(const unsigned short* __restrict__ qkvz, const float* __restrict__ conv_w,
                    unsigned short* __restrict__ qkvs) {
  const int blk = blockIdx.x;
  const int b = blk >> 6;
  const int s0 = (blk & 63) << 4;
  const int t = threadIdx.x;
  const int c0 = t * 8;
  float w[8][4];
#pragma unroll
  for (int e = 0; e < 8; e++) {
    float4v wv = *(const float4v*)&conv_w[(c0 + e) * 4];
    w[e][0] = wv[0]; w[e][1] = wv[1]; w[e][2] = wv[2]; w[e][3] = wv[3];
  }
  const size_t base = (size_t)(b << 10) * NP + c0;
  const bool qk = c0 < 4096;
  const float qsc = (c0 < 2048) ? 0.08838834764831845f : 1.f;
#pragma unroll 1
  for (int i = 0; i < 16; i++) {
    const int s = s0 + i;
    float acc[8] = {0.f, 0.f, 0.f, 0.f, 0.f, 0.f, 0.f, 0.f};
#pragma unroll
    for (int j = 0; j < 4; j++) {
      const int sj = s - 3 + j;
      if (sj >= 0) {
        short8 v8 = *(const short8*)&qkvz[base + (size_t)sj * NP];
#pragma unroll
        for (int e = 0; e < 8; e++) acc[e] = fmaf(b2f((unsigned short)v8[e]), w[e][j], acc[e]);
      }
    }
    float out[8];
#pragma unroll
    for (int e = 0; e < 8; e++) { float xv = acc[e]; out[e] = xv * (1.f / (1.f + expf(-xv))); }
    if (qk) {
      float ss = 0.f;
#pragma unroll
      for (int e = 0; e < 8; e++) ss += out[e] * out[e];
      ss += __shfl_xor(ss, 1); ss += __shfl_xor(ss, 2);
      ss += __shfl_xor(ss, 4); ss += __shfl_xor(ss, 8);
      float sc = rsqrtf(ss + 1e-6f) * qsc;
#pragma unroll
      for (int e = 0; e < 8; e++) out[e] *= sc;
    }
    short8 o;
#pragma unroll
    for (int e = 0; e < 8; e++) o[e] = (short)f2b(out[e]);
    *(short8*)&qkvs[(size_t)((b << 10) + s) * 8192 + c0] = o;
  }
}

// ---- conv_state output: (B,CI,KW) fp32 from pre-conv qkv ----
__global__ void conv_state_k(const unsigned short* __restrict__ qkvz, float* __restrict__ cs) {
  int idx = blockIdx.x * 256 + threadIdx.x;  // < 131072 = 4*8192*4
  int b = idx >> 15;
  int rem = idx & 32767;
  int c = rem >> 2;
  int j = rem & 3;
  cs[idx] = b2f(qkvz[(size_t)(b * 1024 + 1020 + j) * NP + c]);
}

// ---- g / beta from a,b columns ----
__global__ void gb_kernel(const unsigned short* __restrict__ qkvz, const float* __restrict__ A_log,
                          const float* __restrict__ dt_bias, float* __restrict__ g,
                          float* __restrict__ bet) {
  int idx = blockIdx.x * 256 + threadIdx.x;  // < 4096*64
  int m = idx >> 6, n = idx & 63;
  if (n < 32) {
    float a = b2f(qkvz[(size_t)m * NP + 12288 + n]) + dt_bias[n];
    float sp = (a > 20.f) ? a : log1pf(expf(a));
    g[m * 32 + n] = -expf(A_log[n]) * sp;
  } else {
    int nn = n - 32;
    float bb = b2f(qkvz[(size_t)m * NP + 12320 + nn]);
    bet[m * 32 + nn] = 1.f / (1.f + expf(-bb));
  }
}

// ---- chunked delta-rule scan (UT transform), C=64, MFMA throughout ----
__global__ __launch_bounds__(256)
void scan_chunk(const unsigned short* __restrict__ qkvs, const float* __restrict__ g,
                const float* __restrict__ bet, unsigned short* __restrict__ y,
                float* __restrict__ state_out) {
  __shared__ __align__(16) unsigned short Kb[64][128];
  __shared__ __align__(16) unsigned short Qb[64][128];
  __shared__ __align__(16) unsigned short Sb[64][128];
  __shared__ __align__(16) unsigned short Ktt[128][64];
  __shared__ __align__(16) unsigned short Mb[64][64];
  __shared__ __align__(16) unsigned short Nb[64][64];
  __shared__ __align__(16) unsigned short Dbf[64][64];
  __shared__ __align__(16) unsigned short Vt[64][64];   // also reused as obuf
  __shared__ __align__(16) unsigned short Tb[4][16][16];
  __shared__ __align__(16) unsigned short rtmp[64][16];
  __shared__ float Gar[64];
  __shared__ float gamv[64];
  __shared__ float barr[64];
  __shared__ float gcs[2];

  const int bid = blockIdx.x;
  const int b = bid >> 6;
  const int h = (bid >> 1) & 31;
  const int half = bid & 1;
  const int hk = h >> 1;
  const int t = threadIdx.x;
  const int wv = t >> 6, lane = t & 63;
  const int l16 = lane & 15, lg = lane >> 4;
  const int bS = b << 10;

  float4v accS[8] = {};
  for (int idx = t; idx < 64 * 128; idx += 256) (&Sb[0][0])[idx] = 0;

  for (int ch = 0; ch < 16; ch++) {
    const int s0 = ch << 6;
    // ---- phase 1: stage Kb, Qb (swizzled via source permutation), Vt, g/beta ----
    {
#pragma unroll
      for (int rep = 0; rep < 4; rep++) {
        int rb = wv * 16 + rep * 4;
        int i = rb + (lane >> 4);
        int cg = (lane & 15) ^ (i & 7);
        const unsigned short* gk = qkvs + (size_t)(bS + s0 + i) * 8192 + 2048 + hk * 128 + cg * 8;
        gl16(gk, (char*)(&Kb[rb][0] + lane * 8));
        const unsigned short* gq = qkvs + (size_t)(bS + s0 + i) * 8192 + hk * 128 + cg * 8;
        gl16(gq, (char*)(&Qb[rb][0] + lane * 8));
      }
    }
    {
      int tt = t >> 2, q4 = t & 3;
      const unsigned short* gv = qkvs + (size_t)(bS + s0 + tt) * 8192 + 4096 + h * 128 + half * 64 + q4 * 16;
      short8 v0 = *(const short8*)gv;
      short8 v1 = *(const short8*)(gv + 8);
#pragma unroll
      for (int e = 0; e < 8; e++) {
        int v = q4 * 16 + e;
        Vt[v][tt ^ ((v & 7) << 3)] = (unsigned short)v0[e];
        v = q4 * 16 + 8 + e;
        Vt[v][tt ^ ((v & 7) << 3)] = (unsigned short)v1[e];
      }
    }
    if (t < 64) {
      float gt = g[(bS + s0 + t) * 32 + h];
      float bt = bet[(bS + s0 + t) * 32 + h];
#pragma unroll
      for (int d = 1; d < 64; d <<= 1) {
        float o = __shfl_up(gt, d);
        if (t >= d) gt += o;
      }
      Gar[t] = gt;
      gamv[t] = __expf(gt);
      barr[t] = bt;
      if (t == 63) { gcs[0] = gt; gcs[1] = __expf(gt); }
    }
    __syncthreads();

    // ---- phase 2: KK^T -> Mb, QK^T -> Nb; build Ktt ----
    {
      float4v aK[4] = {}, aQ[4] = {};
      const int arow = wv * 16 + l16;
      const int asw = (arow & 7) << 3;
#pragma unroll
      for (int kk = 0; kk < 4; kk++) {
        short8 av = *(const short8*)&Kb[arow][(kk * 32 + lg * 8) ^ asw];
        short8 aq = *(const short8*)&Qb[arow][(kk * 32 + lg * 8) ^ asw];
#pragma unroll
        for (int j = 0; j < 4; j++) {
          int brow = j * 16 + l16;
          short8 bv = *(const short8*)&Kb[brow][(kk * 32 + lg * 8) ^ ((brow & 7) << 3)];
          aK[j] = MFMA32(av, bv, aK[j]);
          aQ[j] = MFMA32(aq, bv, aQ[j]);
        }
      }
#pragma unroll
      for (int j = 0; j < 4; j++) {
#pragma unroll
        for (int reg = 0; reg < 4; reg++) {
          int tt = wv * 16 + lg * 4 + reg;
          int ii = j * 16 + l16;
          float sc = __expf(Gar[tt] - Gar[ii]);
          float mv = (ii < tt) ? aK[j][reg] * barr[tt] * sc : 0.f;
          float nv = (ii <= tt) ? aQ[j][reg] * sc : 0.f;
          Mb[tt][(ii ^ ((tt & 7) << 3))] = f2b(mv);
          Nb[tt][(ii ^ ((tt & 7) << 3))] = f2b(nv);
        }
      }
    }
    {
      int i = t >> 2, q4 = t & 3;
      float sc = __expf(gcs[0] - Gar[i]);
      int isw = (i & 7) << 3;
#pragma unroll
      for (int e8 = 0; e8 < 4; e8++) {
        int d0 = q4 * 32 + e8 * 8;
        short8 kv = *(const short8*)&Kb[i][d0 ^ isw];
#pragma unroll
        for (int e = 0; e < 8; e++) {
          int d = d0 + e;
          Ktt[d][i ^ ((d & 7) << 3)] = f2b(b2f((unsigned short)kv[e]) * sc);
        }
      }
    }
    __syncthreads();

    // ---- phase 3: P0t = S0 K^T; RHS -> Dbf; T-inverse -> Tb ----
    {
      float4v acc[4] = {};
      const int arow = wv * 16 + l16;  // v
      const int asw = (arow & 7) << 3;
#pragma unroll
      for (int kk = 0; kk < 4; kk++) {
        short8 av = *(const short8*)&Sb[arow][(kk * 32 + lg * 8) ^ asw];
#pragma unroll
        for (int j = 0; j < 4; j++) {
          int brow = j * 16 + l16;  // t
          short8 bv = *(const short8*)&Kb[brow][(kk * 32 + lg * 8) ^ ((brow & 7) << 3)];
          acc[j] = MFMA32(av, bv, acc[j]);
        }
      }
#pragma unroll
      for (int j = 0; j < 4; j++) {
#pragma unroll
        for (int reg = 0; reg < 4; reg++) {
          int v = wv * 16 + lg * 4 + reg;
          int tt = j * 16 + l16;
          float vtv = b2f(Vt[v][tt ^ ((v & 7) << 3)]);
          float val = barr[tt] * (vtv - gamv[tt] * acc[j][reg]);
          Dbf[v][tt ^ ((v & 7) << 3)] = f2b(val);
        }
      }
    }
    {
      // T-inverse of diagonal block wv (unit lower)
      float Lrow[16];
#pragma unroll
      for (int i = 0; i < 16; i++)
        Lrow[i] = b2f(Mb[wv * 16 + l16][((wv * 16 + i) ^ ((l16 & 7) << 3))]);
      float Tc[16];
#pragma unroll
      for (int i = 0; i < 16; i++) Tc[i] = (i == l16) ? 1.f : 0.f;
#pragma unroll
      for (int tt = 1; tt < 16; tt++) {
        float s = 0.f;
#pragma unroll
        for (int i = 0; i < 16; i++) {
          if (i < tt)
            s += __int_as_float(__builtin_amdgcn_readlane(__float_as_int(Lrow[i]), tt)) * Tc[i];
        }
        Tc[tt] = ((tt == l16) ? 1.f : 0.f) - s;
      }
      if (lane < 16) {
#pragma unroll
        for (int tt = 0; tt < 16; tt++) Tb[wv][tt][l16] = f2b(Tc[tt]);
      }
    }
    __syncthreads();

    // ---- phase 4: block forward substitution, D = (I+M)^{-1} RHS ----
    {
      short8 a = (short8)(short)0, bT = (short8)(short)0;
      const int arow = wv * 16 + l16;
      if (lg < 2) {
        a = *(const short8*)&Dbf[arow][((lg * 8) ^ ((arow & 7) << 3))];
        bT = *(const short8*)&Tb[0][l16][lg * 8];
      }
      float4v acc0 = {};
      acc0 = MFMA32(a, bT, acc0);
      __syncthreads();
#pragma unroll
      for (int reg = 0; reg < 4; reg++) {
        int v = wv * 16 + lg * 4 + reg;
        Dbf[v][(l16 ^ ((v & 7) << 3))] = f2b(acc0[reg]);
      }
    }
    __syncthreads();
#pragma unroll
    for (int s = 1; s < 4; s++) {
      float4v acc = {};
      const int arow = wv * 16 + l16;
      const int mrow = s * 16 + l16;
#pragma unroll
      for (int j = 0; j < 3; j++) {
        if (j < s) {
          short8 a = (short8)(short)0, bM = (short8)(short)0;
          if (lg < 2) {
            a  = *(const short8*)&Dbf[arow][((j * 16 + lg * 8) ^ ((arow & 7) << 3))];
            bM = *(const short8*)&Mb[mrow][((j * 16 + lg * 8) ^ ((mrow & 7) << 3))];
          }
          acc = MFMA32(a, bM, acc);
        }
      }
#pragma unroll
      for (int reg = 0; reg < 4; reg++) {
        int v = wv * 16 + lg * 4 + reg;
        float rt = b2f(Dbf[v][((s * 16 + l16) ^ ((v & 7) << 3))]);
        rtmp[v][l16] = f2b(rt - acc[reg]);
      }
      __syncthreads();
      short8 a2 = (short8)(short)0, bT = (short8)(short)0;
      if (lg < 2) {
        a2 = *(const short8*)&rtmp[wv * 16 + l16][lg * 8];
        bT = *(const short8*)&Tb[s][l16][lg * 8];
      }
      float4v acc2 = {};
      acc2 = MFMA32(a2, bT, acc2);
      __syncthreads();
#pragma unroll
      for (int reg = 0; reg < 4; reg++) {
        int v = wv * 16 + lg * 4 + reg;
        Dbf[v][((s * 16 + l16) ^ ((v & 7) << 3))] = f2b(acc2[reg]);
      }
      __syncthreads();
    }

    // ---- phase 5: O = diag(gam) Q S0^T + N D ----
    {
      float4v acc[4] = {};
      const int arow = wv * 16 + l16;  // t
      const int asw = (arow & 7) << 3;
#pragma unroll
      for (int kk = 0; kk < 4; kk++) {
        short8 aq = *(const short8*)&Qb[arow][(kk * 32 + lg * 8) ^ asw];
#pragma unroll
        for (int j = 0; j < 4; j++) {
          int brow = j * 16 + l16;  // v
          short8 bs = *(const short8*)&Sb[brow][(kk * 32 + lg * 8) ^ ((brow & 7) << 3)];
          acc[j] = MFMA32(aq, bs, acc[j]);
        }
      }
#pragma unroll
      for (int j = 0; j < 4; j++) {
#pragma unroll
        for (int reg = 0; reg < 4; reg++) {
          int tt = wv * 16 + lg * 4 + reg;
          acc[j][reg] *= gamv[tt];
        }
      }
#pragma unroll
      for (int kk = 0; kk < 2; kk++) {
        short8 an = *(const short8*)&Nb[arow][(kk * 32 + lg * 8) ^ asw];
#pragma unroll
        for (int j = 0; j < 4; j++) {
          int brow = j * 16 + l16;  // v
          short8 bd = *(const short8*)&Dbf[brow][(kk * 32 + lg * 8) ^ ((brow & 7) << 3)];
          acc[j] = MFMA32(an, bd, acc[j]);
        }
      }
      __syncthreads();  // Vt consumed; reuse as obuf
#pragma unroll
      for (int j = 0; j < 4; j++) {
#pragma unroll
        for (int reg = 0; reg < 4; reg++) {
          int tt = wv * 16 + lg * 4 + reg;
          int v = j * 16 + l16;
          Vt[tt][v ^ ((tt & 7) << 3)] = f2b(acc[j][reg]);
        }
      }
    }
    __syncthreads();
    {
      int tt = t >> 2, q4 = t & 3;
      int sw = (tt & 7) << 3;
      unsigned short* yg = y + (size_t)(bS + s0 + tt) * 4096 + h * 128 + half * 64 + q4 * 16;
      short8 o0 = *(const short8*)&Vt[tt][(q4 * 16) ^ sw];
      short8 o1 = *(const short8*)&Vt[tt][(q4 * 16 + 8) ^ sw];
      *(short8*)yg = o0;
      *(short8*)(yg + 8) = o1;
    }

    // ---- phase 6: state update S = gamC * S + D^T Ktt ----
    {
      float gC = gcs[1];
#pragma unroll
      for (int dt = 0; dt < 8; dt++)
#pragma unroll
        for (int reg = 0; reg < 4; reg++) accS[dt][reg] *= gC;
      const int arow = wv * 16 + l16;  // v
      const int asw = (arow & 7) << 3;
#pragma unroll
      for (int kk = 0; kk < 2; kk++) {
        short8 ad = *(const short8*)&Dbf[arow][(kk * 32 + lg * 8) ^ asw];
#pragma unroll
        for (int dt = 0; dt < 8; dt++) {
          int brow = dt * 16 + l16;  // d
          short8 bk = *(const short8*)&Ktt[brow][(kk * 32 + lg * 8) ^ ((brow & 7) << 3)];
          accS[dt] = MFMA32(ad, bk, accS[dt]);
        }
      }
      __syncthreads();
#pragma unroll
      for (int dt = 0; dt < 8; dt++) {
#pragma unroll
        for (int reg = 0; reg < 4; reg++) {
          int v = wv * 16 + lg * 4 + reg;
          int d = dt * 16 + l16;
          Sb[v][d ^ ((v & 7) << 3)] = f2b(accS[dt][reg]);
        }
      }
    }
    __syncthreads();
  }

  // final state writeout (fp32)
#pragma unroll
  for (int dt = 0; dt < 8; dt++) {
#pragma unroll
    for (int reg = 0; reg < 4; reg++) {
      int v = wv * 16 + lg * 4 + reg;
      int d = dt * 16 + l16;
      state_out[((size_t)((b * 32 + h) * 128 + half * 64 + v)) * 128 + d] = accS[dt][reg];
    }
  }
}

// ---- RMSNorm over DV * norm_w * silu(z) -> yn bf16 ----
__global__ __launch_bounds__(256)
void rms_silu(const unsigned short* __restrict__ y, const unsigned short* __restrict__ qkvz,
              const float* __restrict__ nw, unsigned short* __restrict__ yn) {
  int m = blockIdx.x;
  int t = threadIdx.x;
  int head = t >> 3, oct = t & 7;
  int vb = head * 128 + oct * 16;
  const unsigned short* yp = y + (size_t)m * 4096 + vb;
  float yy[16];
  short8 y0 = *(const short8*)yp, y1 = *(const short8*)(yp + 8);
#pragma unroll
  for (int e = 0; e < 8; e++) { yy[e] = b2f((unsigned short)y0[e]); yy[8 + e] = b2f((unsigned short)y1[e]); }
  float ss = 0.f;
#pragma unroll
  for (int e = 0; e < 16; e++) ss += yy[e] * yy[e];
  ss += __shfl_xor(ss, 1); ss += __shfl_xor(ss, 2); ss += __shfl_xor(ss, 4);
  float rinv = rsqrtf(ss * (1.f / 128.f) + 1e-6f);
  const unsigned short* zp = qkvz + (size_t)m * NP + 8192 + vb;
  short8 z0 = *(const short8*)zp, z1 = *(const short8*)(zp + 8);
  short8 o0, o1;
#pragma unroll
  for (int e = 0; e < 8; e++) {
    float z = b2f((unsigned short)z0[e]);
    float v = nw[oct * 16 + e] * yy[e] * rinv * (z / (1.f + expf(-z)));
    o0[e] = (short)f2b(v);
    z = b2f((unsigned short)z1[e]);
    v = nw[oct * 16 + 8 + e] * yy[8 + e] * rinv * (z / (1.f + expf(-z)));
    o1[e] = (short)f2b(v);
  }
  unsigned short* op = yn + (size_t)m * 4096 + vb;
  *(short8*)op = o0;
  *(short8*)(op + 8) = o1;
}

extern "C" void kernel_launch(void* const* d_in, const int* in_sizes, int n_in,
                              void* d_out, int out_size, void* d_ws, size_t ws_size,
                              hipStream_t stream) {
  if (ws_size < WS_NEED) return;  // guard: fail with clean absmax, not a fault

  const float* x     = (const float*)d_in[0];
  const float* Wqkv  = (const float*)d_in[1];
  const float* Wz    = (const float*)d_in[2];
  const float* Wa    = (const float*)d_in[3];
  const float* Wb    = (const float*)d_in[4];
  const float* convw = (const float*)d_in[5];
  const float* Alog  = (const float*)d_in[6];
  const float* dtb   = (const float*)d_in[7];
  const float* nw    = (const float*)d_in[8];
  const float* Wout  = (const float*)d_in[9];

  char* ws = (char*)d_ws;
  unsigned short* qkvz = (unsigned short*)(ws + OFF_QKVZ);
  unsigned short* xb   = (unsigned short*)(ws + OFF_XB);
  unsigned short* wcat = (unsigned short*)(ws + OFF_WCAT);
  unsigned short* qkvs = (unsigned short*)(ws + OFF_QKVS);
  unsigned short* ynb  = (unsigned short*)(ws + OFF_YN);
  unsigned short* wob  = (unsigned short*)(ws + OFF_WOB);
  float* gbuf          = (float*)(ws + OFF_G);
  float* bbuf          = (float*)(ws + OFF_BET);

  float* outp       = (float*)d_out;
  float* conv_state = outp + 8388608;             // B*S*H
  float* state      = outp + 8388608 + 131072;    // + B*CI*KW
  unsigned short* ybuf = (unsigned short*)d_out;  // y bf16 scratch over outp region

  castk<<<8192, 256, 0, stream>>>(x, xb, 2097152);
  prep_wcat<<<25088, 256, 0, stream>>>(Wqkv, Wz, Wa, Wb, wcat);

  // GEMM1: 1568 blocks (32 bm x 49 bn), bn-major XCD slabs, 2 blocks/CU
  gemm_db<true, unsigned short><<<1568, 512, 0, stream>>>(xb, wcat, qkvz, 2048, 32, 49, NP);

  conv_silu_norm<<<256, 1024, 0, stream>>>(qkvz, convw, qkvs);
  conv_state_k<<<512, 256, 0, stream>>>(qkvz, conv_state);
  gb_kernel<<<1024, 256, 0, stream>>>(qkvz, Alog, dtb, gbuf, bbuf);

  scan_chunk<<<256, 256, 0, stream>>>(qkvs, gbuf, bbuf, ybuf, state);

  rms_silu<<<4096, 256, 0, stream>>>(ybuf, qkvz, nw, ynb);
  castk<<<8192, 256, 0, stream>>>(Wout, wob, 2097152);

  // GEMM2: 256 blocks (32 bm x 8 bn), bm-major
  gemm_db<false, float><<<256, 512, 0, stream>>>(ynb, wob, outp, 4096, 32, 8, 2048);
}

// Round 13
// 566.455 us; speedup vs baseline: 1.0474x; 1.0474x over previous
//
#include <hip/hip_runtime.h>
#include <cstdint>
#include <cstddef>

typedef __attribute__((ext_vector_type(8))) short short8;
typedef __attribute__((ext_vector_type(4))) short short4v;
typedef __attribute__((ext_vector_type(4))) float float4v;

#define DEV static __device__ __forceinline__

DEV float b2f(unsigned short u) { return __uint_as_float(((unsigned int)u) << 16); }
DEV unsigned short f2b(float f) {
  unsigned int u = __float_as_uint(f);
  u = (u + 0x7fffu + ((u >> 16) & 1u)) >> 16;
  return (unsigned short)u;
}

#define MFMA32(a, b, c) __builtin_amdgcn_mfma_f32_16x16x32_bf16(a, b, c, 0, 0, 0)

// ---- problem sizes ----
static constexpr int NP   = 12416;  // qkvz stride: 8192 qkv + 4096 z + 32 a + 32 b + 64 pad
static constexpr int NPAD = 12544;  // wcat rows padded to 49*256 for 256-col B tiles

// ---- ws layout (bytes), lifetime-overlaid ----
static constexpr size_t OFF_QKVZ = 0;
static constexpr size_t SZ_QKVZ  = (size_t)4096*NP*2;        // 101,711,872
static constexpr size_t OFF_XB   = SZ_QKVZ;
static constexpr size_t SZ_XB    = (size_t)4096*2048*2;      // 16,777,216
static constexpr size_t OFF_WCAT = OFF_XB + SZ_XB;
static constexpr size_t SZ_WCAT  = (size_t)NPAD*2048*2;      // 51,380,224
static constexpr size_t OFF_QKVS = OFF_XB;                   // overlays xb+wcat after GEMM1
static constexpr size_t SZ_QKVS  = (size_t)4096*8192*2;      // 67,108,864
static constexpr size_t OFF_G    = OFF_XB + SZ_QKVS;
static constexpr size_t OFF_BET  = OFF_G + (size_t)4096*32*4;
static constexpr size_t OFF_YN   = OFF_XB;                   // after scan
static constexpr size_t SZ_YN    = (size_t)4096*4096*2;
static constexpr size_t OFF_WOB  = OFF_YN + SZ_YN;
static constexpr size_t WS_NEED  = OFF_WCAT + SZ_WCAT;       // 169,869,312

// ---- helpers ----
DEV void gl16(const unsigned short* g, char* l) {
  __builtin_amdgcn_global_load_lds((const __attribute__((address_space(1))) unsigned int*)g,
                                   (__attribute__((address_space(3))) unsigned int*)l,
                                   16, 0, 0);
}

DEV void store_out(unsigned short* C, size_t off, float v) { C[off] = f2b(v); }
DEV void store_out(float* C, size_t off, float v)          { C[off] = v; }

// ---- fused prep: cast x -> bf16, build wcat [12544][2048] bf16 ----
__global__ void prep_all(const float* __restrict__ x, const float* __restrict__ Wqkv,
                         const float* __restrict__ Wz, const float* __restrict__ Wa,
                         const float* __restrict__ Wb, unsigned short* __restrict__ xb,
                         unsigned short* __restrict__ wcat) {
  size_t idx = (size_t)blockIdx.x * 256 + threadIdx.x;
  if (idx < 2097152) {
    float4v v = ((const float4v*)x)[idx];
    short4v o;
    o[0] = (short)f2b(v[0]); o[1] = (short)f2b(v[1]);
    o[2] = (short)f2b(v[2]); o[3] = (short)f2b(v[3]);
    ((short4v*)xb)[idx] = o;
  } else {
    size_t e4 = idx - 2097152;
    if (e4 >= (size_t)NPAD * 2048 / 4) return;
    size_t e = e4 * 4;
    int row = (int)(e >> 11);
    int col = (int)(e & 2047);
    float4v v;
    if (row < 8192)       v = *(const float4v*)&Wqkv[(size_t)row * 2048 + col];
    else if (row < 12288) v = *(const float4v*)&Wz[(size_t)(row - 8192) * 2048 + col];
    else if (row < 12320) v = *(const float4v*)&Wa[(size_t)(row - 12288) * 2048 + col];
    else if (row < 12352) v = *(const float4v*)&Wb[(size_t)(row - 12320) * 2048 + col];
    else                  v = (float4v){0.f, 0.f, 0.f, 0.f};
    short4v o;
    o[0] = (short)f2b(v[0]); o[1] = (short)f2b(v[1]);
    o[2] = (short)f2b(v[2]); o[3] = (short)f2b(v[3]);
    *(short4v*)&wcat[e] = o;
  }
}

// ======= 128x256 double-buffered bf16 MFMA GEMM (round-12 champion) =======
template <bool BNMAJOR, typename OutT>
__global__ __launch_bounds__(512, 4)
void gemm_db(const unsigned short* __restrict__ A, const unsigned short* __restrict__ B,
             OutT* __restrict__ C, int K, int nbm, int nbn, int NC) {
  constexpr int ASZ  = 128 * 64;          // 8 KB
  constexpr int SLOT = ASZ + 16384;       // 24 KB
  __shared__ __align__(16) char sm[2 * SLOT];
  const int t = threadIdx.x;
  const int cpx = gridDim.x >> 3;
  int wg = blockIdx.x;
  wg = (wg & 7) * cpx + (wg >> 3);        // bijective XCD swizzle (grid % 8 == 0)
  const int bm = BNMAJOR ? (wg % nbm) : (wg / nbn);
  const int bn = BNMAJOR ? (wg / nbm) : (wg % nbn);

  const int wv = t >> 6, lane = t & 63;
  const int l16 = lane & 15, lg = lane >> 4;
  const int wm = (wv >> 2) * 64;
  const int wn = (wv & 3) * 64;
  const int rsw = (lg ^ ((l16 >> 1) & 3)) << 4;

  size_t aoff, boff[2];
  {
    int L = t * 16;
    int row = L >> 6;
    int c = ((L >> 4) & 3) ^ ((row >> 1) & 3);
    aoff = (size_t)(bm * 128 + row) * K + (c << 3);
  }
#pragma unroll
  for (int r = 0; r < 2; r++) {
    int L = r * 8192 + t * 16;
    int row = L >> 6;
    int c = ((L >> 4) & 3) ^ ((row >> 1) & 3);
    boff[r] = (size_t)(bn * 256 + row) * K + (c << 3);
  }

  float4v acc[4][4] = {};
  const int NKT = K >> 5;

#define STAGE(J)                                                              \
  do {                                                                        \
    const size_t ko = (size_t)(J) * 32;                                       \
    char* slot = sm + ((J) & 1) * SLOT;                                       \
    gl16(A + aoff + ko, slot + t * 16);                                       \
    gl16(B + boff[0] + ko, slot + ASZ + t * 16);                              \
    gl16(B + boff[1] + ko, slot + ASZ + 8192 + t * 16);                       \
  } while (0)

  STAGE(0);
  asm volatile("s_waitcnt vmcnt(0)" ::: "memory");
  __builtin_amdgcn_s_barrier();

  for (int j = 0; j < NKT; j++) {
    char* ab = sm + (j & 1) * SLOT;
    char* bb = ab + ASZ;
    if (j + 1 < NKT) STAGE(j + 1);
    short8 av[4], bv[4];
#pragma unroll
    for (int mi = 0; mi < 4; mi++)
      av[mi] = *(const short8*)(ab + (wm + mi * 16 + l16) * 64 + rsw);
#pragma unroll
    for (int nn = 0; nn < 4; nn++)
      bv[nn] = *(const short8*)(bb + (wn + nn * 16 + l16) * 64 + rsw);
    __builtin_amdgcn_s_setprio(1);
#pragma unroll
    for (int mi = 0; mi < 4; mi++)
#pragma unroll
      for (int nn = 0; nn < 4; nn++)
        acc[mi][nn] = MFMA32(av[mi], bv[nn], acc[mi][nn]);
    __builtin_amdgcn_s_setprio(0);
    asm volatile("s_waitcnt vmcnt(0)" ::: "memory");
    __builtin_amdgcn_s_barrier();
  }
#undef STAGE

#pragma unroll
  for (int mi = 0; mi < 4; mi++) {
    int row0 = bm * 128 + wm + mi * 16 + lg * 4;
#pragma unroll
    for (int nn = 0; nn < 4; nn++) {
      int col = bn * 256 + wn + nn * 16 + l16;
      if (col < NC) {
#pragma unroll
        for (int rr = 0; rr < 4; rr++)
          store_out(C, (size_t)(row0 + rr) * NC + col, acc[mi][nn][rr]);
      }
    }
  }
}

// ---- conv(KW=4)+silu+norm + g/beta + conv_state, fused ----
__global__ __launch_bounds__(1024)
void conv_fused(const unsigned short* __restrict__ qkvz, const float* __restrict__ conv_w,
                const float* __restrict__ A_log, const float* __restrict__ dt_bias,
                unsigned short* __restrict__ qkvs, float* __restrict__ gbuf,
                float* __restrict__ bbuf, float* __restrict__ cs) {
  const int blk = blockIdx.x;
  const int b = blk >> 6;
  const int s0 = (blk & 63) << 4;
  const int t = threadIdx.x;
  const int c0 = t * 8;
  float w[8][4];
#pragma unroll
  for (int e = 0; e < 8; e++) {
    float4v wv = *(const float4v*)&conv_w[(c0 + e) * 4];
    w[e][0] = wv[0]; w[e][1] = wv[1]; w[e][2] = wv[2]; w[e][3] = wv[3];
  }
  const size_t base = (size_t)(b << 10) * NP + c0;
  const bool qk = c0 < 4096;
  const float qsc = (c0 < 2048) ? 0.08838834764831845f : 1.f;
#pragma unroll 1
  for (int i = 0; i < 16; i++) {
    const int s = s0 + i;
    float acc[8] = {0.f, 0.f, 0.f, 0.f, 0.f, 0.f, 0.f, 0.f};
#pragma unroll
    for (int j = 0; j < 4; j++) {
      const int sj = s - 3 + j;
      if (sj >= 0) {
        short8 v8 = *(const short8*)&qkvz[base + (size_t)sj * NP];
#pragma unroll
        for (int e = 0; e < 8; e++) acc[e] = fmaf(b2f((unsigned short)v8[e]), w[e][j], acc[e]);
      }
    }
    float out[8];
#pragma unroll
    for (int e = 0; e < 8; e++) { float xv = acc[e]; out[e] = xv * (1.f / (1.f + expf(-xv))); }
    if (qk) {
      float ss = 0.f;
#pragma unroll
      for (int e = 0; e < 8; e++) ss += out[e] * out[e];
      ss += __shfl_xor(ss, 1); ss += __shfl_xor(ss, 2);
      ss += __shfl_xor(ss, 4); ss += __shfl_xor(ss, 8);
      float sc = rsqrtf(ss + 1e-6f) * qsc;
#pragma unroll
      for (int e = 0; e < 8; e++) out[e] *= sc;
    }
    short8 o;
#pragma unroll
    for (int e = 0; e < 8; e++) o[e] = (short)f2b(out[e]);
    *(short8*)&qkvs[(size_t)((b << 10) + s) * 8192 + c0] = o;
  }
  // g / beta: thread t -> (s = s0 + t>>6, n = t&63)
  {
    int m = (b << 10) + s0 + (t >> 6);
    int n = t & 63;
    if (n < 32) {
      float a = b2f(qkvz[(size_t)m * NP + 12288 + n]) + dt_bias[n];
      float sp = (a > 20.f) ? a : log1pf(expf(a));
      gbuf[m * 32 + n] = -expf(A_log[n]) * sp;
    } else {
      int nn = n - 32;
      float bb = b2f(qkvz[(size_t)m * NP + 12320 + nn]);
      bbuf[m * 32 + nn] = 1.f / (1.f + expf(-bb));
    }
  }
  // conv_state: only the last s-chunk block per batch
  if ((blk & 63) == 63) {
#pragma unroll
    for (int j = 0; j < 4; j++)
#pragma unroll
      for (int e = 0; e < 8; e++)
        cs[((size_t)b * 8192 + c0 + e) * 4 + j] =
            b2f(qkvz[(size_t)(b * 1024 + 1020 + j) * NP + c0 + e]);
  }
}

// ---- chunked delta-rule scan v2: 4 barriers/chunk, fused MEGA phase,
//      per-wave-private fwd-subst, K/Q gl16 prefetch overlapped ----
__global__ __launch_bounds__(256)
void scan_chunk(const unsigned short* __restrict__ qkvs, const float* __restrict__ g,
                const float* __restrict__ bet, unsigned short* __restrict__ y,
                float* __restrict__ state_out) {
  __shared__ __align__(16) unsigned short Kb[64][128];
  __shared__ __align__(16) unsigned short Qb[64][128];
  __shared__ __align__(16) unsigned short Sb[64][128];
  __shared__ __align__(16) unsigned short Ktt[128][64];
  __shared__ __align__(16) unsigned short Mb[64][64];   // M; reused as obuf in P5
  __shared__ __align__(16) unsigned short Nb[64][64];
  __shared__ __align__(16) unsigned short Dbf[64][64];
  __shared__ __align__(16) unsigned short Vt[64][64];
  __shared__ __align__(16) unsigned short Tb[4][16][16];
  __shared__ __align__(16) unsigned short rtmp[64][16];
  __shared__ float Gar[64];
  __shared__ float gamv[64];
  __shared__ float barr[64];
  __shared__ float gcs[2];

  const int bid = blockIdx.x;
  const int b = bid >> 6;
  const int h = (bid >> 1) & 31;
  const int half = bid & 1;
  const int hk = h >> 1;
  const int t = threadIdx.x;
  const int wv = t >> 6, lane = t & 63;
  const int l16 = lane & 15, lg = lane >> 4;
  const int bS = b << 10;
  const int arow = wv * 16 + l16;
  const int asw = (arow & 7) << 3;

  float4v accS[8] = {};
  for (int idx = t; idx < 64 * 128; idx += 256) (&Sb[0][0])[idx] = 0;

#define STAGE_KQ(CH)                                                          \
  do {                                                                        \
    const int ss0 = (CH) << 6;                                                \
    _Pragma("unroll") for (int rep = 0; rep < 4; rep++) {                     \
      int rb = wv * 16 + rep * 4;                                             \
      int i = rb + (lane >> 4);                                               \
      int cg = (lane & 15) ^ (i & 7);                                         \
      gl16(qkvs + (size_t)(bS + ss0 + i) * 8192 + 2048 + hk * 128 + cg * 8,   \
           (char*)(&Kb[rb][0] + lane * 8));                                   \
      gl16(qkvs + (size_t)(bS + ss0 + i) * 8192 + hk * 128 + cg * 8,          \
           (char*)(&Qb[rb][0] + lane * 8));                                   \
    }                                                                         \
  } while (0)

  const int vtt = t >> 2, vq4 = t & 3;
  STAGE_KQ(0);
  short8 v0, v1;
  {
    const unsigned short* gv = qkvs + (size_t)(bS + vtt) * 8192 + 4096 + h * 128 + half * 64 + vq4 * 16;
    v0 = *(const short8*)gv;
    v1 = *(const short8*)(gv + 8);
  }

  for (int ch = 0; ch < 16; ch++) {
    const int s0 = ch << 6;
    // ---- P1: write Vt; g/beta load + prefix scan ----
#pragma unroll
    for (int e = 0; e < 8; e++) {
      int v = vq4 * 16 + e;
      Vt[v][vtt ^ ((v & 7) << 3)] = (unsigned short)v0[e];
      v = vq4 * 16 + 8 + e;
      Vt[v][vtt ^ ((v & 7) << 3)] = (unsigned short)v1[e];
    }
    if (t < 64) {
      float gt = g[(bS + s0 + t) * 32 + h];
      float bt = bet[(bS + s0 + t) * 32 + h];
#pragma unroll
      for (int d = 1; d < 64; d <<= 1) {
        float o = __shfl_up(gt, d);
        if (t >= d) gt += o;
      }
      Gar[t] = gt;
      gamv[t] = __expf(gt);
      barr[t] = bt;
      if (t == 63) { gcs[0] = gt; gcs[1] = __expf(gt); }
    }
    asm volatile("s_waitcnt vmcnt(0)" ::: "memory");  // K/Q gl16 landed
    __syncthreads();  // bar A

    // ---- MEGA: KK^T, QK^T, S0K^T, QS0^T (64 MFMA/wave) ----
    float4v aK[4] = {}, aQ[4] = {}, aS[4] = {}, aO[4] = {};
#pragma unroll
    for (int kk = 0; kk < 4; kk++) {
      short8 av  = *(const short8*)&Kb[arow][(kk * 32 + lg * 8) ^ asw];
      short8 aq  = *(const short8*)&Qb[arow][(kk * 32 + lg * 8) ^ asw];
      short8 as_ = *(const short8*)&Sb[arow][(kk * 32 + lg * 8) ^ asw];
#pragma unroll
      for (int j = 0; j < 4; j++) {
        int brow = j * 16 + l16;
        short8 bk = *(const short8*)&Kb[brow][(kk * 32 + lg * 8) ^ ((brow & 7) << 3)];
        short8 bs = *(const short8*)&Sb[brow][(kk * 32 + lg * 8) ^ ((brow & 7) << 3)];
        aK[j] = MFMA32(av, bk, aK[j]);
        aQ[j] = MFMA32(aq, bk, aQ[j]);
        aS[j] = MFMA32(as_, bk, aS[j]);
        aO[j] = MFMA32(aq, bs, aO[j]);
      }
    }
    // writebacks: M, N, RHS->Dbf, aO scale, Ktt
#pragma unroll
    for (int j = 0; j < 4; j++) {
#pragma unroll
      for (int reg = 0; reg < 4; reg++) {
        int tt = wv * 16 + lg * 4 + reg;
        int ii = j * 16 + l16;
        float sc = __expf(Gar[tt] - Gar[ii]);
        float mv = (ii < tt) ? aK[j][reg] * barr[tt] * sc : 0.f;
        float nv = (ii <= tt) ? aQ[j][reg] * sc : 0.f;
        Mb[tt][(ii ^ ((tt & 7) << 3))] = f2b(mv);
        Nb[tt][(ii ^ ((tt & 7) << 3))] = f2b(nv);
        // RHS (v = tt index role swap: rows of aS are v)
        int v = tt;
        float vtv = b2f(Vt[v][ii ^ ((v & 7) << 3)]);
        float val = barr[ii] * (vtv - gamv[ii] * aS[j][reg]);
        Dbf[v][ii ^ ((v & 7) << 3)] = f2b(val);
        aO[j][reg] *= gamv[tt];
      }
    }
    {
      int i = t >> 2, q4 = t & 3;
      float sc = __expf(gcs[0] - Gar[i]);
      int isw = (i & 7) << 3;
#pragma unroll
      for (int e8 = 0; e8 < 4; e8++) {
        int d0 = q4 * 32 + e8 * 8;
        short8 kv = *(const short8*)&Kb[i][d0 ^ isw];
#pragma unroll
        for (int e = 0; e < 8; e++) {
          int d = d0 + e;
          Ktt[d][i ^ ((d & 7) << 3)] = f2b(b2f((unsigned short)kv[e]) * sc);
        }
      }
    }
    __builtin_amdgcn_sched_barrier(0);
    // ---- T-inverse of own diagonal block (reads own-wave Mb rows) ----
    {
      float Lrow[16];
#pragma unroll
      for (int i = 0; i < 16; i++)
        Lrow[i] = b2f(Mb[wv * 16 + l16][((wv * 16 + i) ^ ((l16 & 7) << 3))]);
      float Tc[16];
#pragma unroll
      for (int i = 0; i < 16; i++) Tc[i] = (i == l16) ? 1.f : 0.f;
#pragma unroll
      for (int tt = 1; tt < 16; tt++) {
        float s = 0.f;
#pragma unroll
        for (int i = 0; i < 16; i++) {
          if (i < tt)
            s += __int_as_float(__builtin_amdgcn_readlane(__float_as_int(Lrow[i]), tt)) * Tc[i];
        }
        Tc[tt] = ((tt == l16) ? 1.f : 0.f) - s;
      }
      if (lane < 16) {
#pragma unroll
        for (int tt = 0; tt < 16; tt++) Tb[wv][tt][l16] = f2b(Tc[tt]);
      }
    }
    __syncthreads();  // bar B (publishes Mb/Nb/Dbf/Ktt/Tb)

    // prefetch next chunk K/Q (Kb/Qb fully consumed) + V regs
    if (ch + 1 < 16) {
      STAGE_KQ(ch + 1);
      const unsigned short* gv = qkvs + (size_t)(bS + ((ch + 1) << 6) + vtt) * 8192 + 4096 + h * 128 + half * 64 + vq4 * 16;
      v0 = *(const short8*)gv;
      v1 = *(const short8*)(gv + 8);
    }

    // ---- FWD-SUBST (per-wave private v-strip; no barriers) ----
    {
      short8 a = (short8)(short)0, bT = (short8)(short)0;
      if (lg < 2) {
        a = *(const short8*)&Dbf[arow][((lg * 8) ^ asw)];
        bT = *(const short8*)&Tb[0][l16][lg * 8];
      }
      float4v acc0 = {};
      acc0 = MFMA32(a, bT, acc0);
      __builtin_amdgcn_sched_barrier(0);
#pragma unroll
      for (int reg = 0; reg < 4; reg++) {
        int v = wv * 16 + lg * 4 + reg;
        Dbf[v][(l16 ^ ((v & 7) << 3))] = f2b(acc0[reg]);
      }
      __builtin_amdgcn_sched_barrier(0);
    }
#pragma unroll
    for (int s = 1; s < 4; s++) {
      float4v acc = {};
      const int mrow = s * 16 + l16;
#pragma unroll
      for (int j = 0; j < 3; j++) {
        if (j < s) {
          short8 a = (short8)(short)0, bM = (short8)(short)0;
          if (lg < 2) {
            a  = *(const short8*)&Dbf[arow][((j * 16 + lg * 8) ^ asw)];
            bM = *(const short8*)&Mb[mrow][((j * 16 + lg * 8) ^ ((mrow & 7) << 3))];
          }
          acc = MFMA32(a, bM, acc);
        }
      }
      __builtin_amdgcn_sched_barrier(0);
#pragma unroll
      for (int reg = 0; reg < 4; reg++) {
        int v = wv * 16 + lg * 4 + reg;
        float rt = b2f(Dbf[v][((s * 16 + l16) ^ ((v & 7) << 3))]);
        rtmp[v][l16] = f2b(rt - acc[reg]);
      }
      __builtin_amdgcn_sched_barrier(0);
      short8 a2 = (short8)(short)0, bT = (short8)(short)0;
      if (lg < 2) {
        a2 = *(const short8*)&rtmp[wv * 16 + l16][lg * 8];
        bT = *(const short8*)&Tb[s][l16][lg * 8];
      }
      float4v acc2 = {};
      acc2 = MFMA32(a2, bT, acc2);
      __builtin_amdgcn_sched_barrier(0);
#pragma unroll
      for (int reg = 0; reg < 4; reg++) {
        int v = wv * 16 + lg * 4 + reg;
        Dbf[v][((s * 16 + l16) ^ ((v & 7) << 3))] = f2b(acc2[reg]);
      }
      __builtin_amdgcn_sched_barrier(0);
    }
    __syncthreads();  // bar C (publishes final Dbf)

    // ---- P5: O = aO + N D -> obuf (Mb, now dead) ----
#pragma unroll
    for (int kk = 0; kk < 2; kk++) {
      short8 an = *(const short8*)&Nb[arow][(kk * 32 + lg * 8) ^ asw];
#pragma unroll
      for (int j = 0; j < 4; j++) {
        int brow = j * 16 + l16;
        short8 bd = *(const short8*)&Dbf[brow][(kk * 32 + lg * 8) ^ ((brow & 7) << 3)];
        aO[j] = MFMA32(an, bd, aO[j]);
      }
    }
#pragma unroll
    for (int j = 0; j < 4; j++) {
#pragma unroll
      for (int reg = 0; reg < 4; reg++) {
        int tt = wv * 16 + lg * 4 + reg;
        int v = j * 16 + l16;
        Mb[tt][v ^ ((tt & 7) << 3)] = f2b(aO[j][reg]);
      }
    }
    // ---- P6: accS = gamC*accS + D^T Ktt; write Sb ----
    {
      float gC = gcs[1];
#pragma unroll
      for (int dt = 0; dt < 8; dt++)
#pragma unroll
        for (int reg = 0; reg < 4; reg++) accS[dt][reg] *= gC;
#pragma unroll
      for (int kk = 0; kk < 2; kk++) {
        short8 ad = *(const short8*)&Dbf[arow][(kk * 32 + lg * 8) ^ asw];
#pragma unroll
        for (int dt = 0; dt < 8; dt++) {
          int brow = dt * 16 + l16;
          short8 bk = *(const short8*)&Ktt[brow][(kk * 32 + lg * 8) ^ ((brow & 7) << 3)];
          accS[dt] = MFMA32(ad, bk, accS[dt]);
        }
      }
#pragma unroll
      for (int dt = 0; dt < 8; dt++) {
#pragma unroll
        for (int reg = 0; reg < 4; reg++) {
          int v = wv * 16 + lg * 4 + reg;
          int d = dt * 16 + l16;
          Sb[v][d ^ ((v & 7) << 3)] = f2b(accS[dt][reg]);
        }
      }
    }
    __syncthreads();  // bar D (publishes obuf for y store; Sb for next chunk)

    // ---- y store from obuf (Mb) ----
    {
      int tt = t >> 2, q4 = t & 3;
      int sw = (tt & 7) << 3;
      unsigned short* yg = y + (size_t)(bS + s0 + tt) * 4096 + h * 128 + half * 64 + q4 * 16;
      short8 o0 = *(const short8*)&Mb[tt][(q4 * 16) ^ sw];
      short8 o1 = *(const short8*)&Mb[tt][(q4 * 16 + 8) ^ sw];
      *(short8*)yg = o0;
      *(short8*)(yg + 8) = o1;
    }
  }
#undef STAGE_KQ

  // final state writeout (fp32)
#pragma unroll
  for (int dt = 0; dt < 8; dt++) {
#pragma unroll
    for (int reg = 0; reg < 4; reg++) {
      int v = wv * 16 + lg * 4 + reg;
      int d = dt * 16 + l16;
      state_out[((size_t)((b * 32 + h) * 128 + half * 64 + v)) * 128 + d] = accS[dt][reg];
    }
  }
}

// ---- RMSNorm*silu(z) fused with Wout cast ----
__global__ __launch_bounds__(256)
void rms_wcast(const unsigned short* __restrict__ y, const unsigned short* __restrict__ qkvz,
               const float* __restrict__ nw, unsigned short* __restrict__ yn,
               const float* __restrict__ Wout, unsigned short* __restrict__ wob) {
  int blk = blockIdx.x;
  int t = threadIdx.x;
  if (blk >= 4096) {
    int idx = (blk - 4096) * 256 + t;
    float4v v = ((const float4v*)Wout)[idx];
    short4v o;
    o[0] = (short)f2b(v[0]); o[1] = (short)f2b(v[1]);
    o[2] = (short)f2b(v[2]); o[3] = (short)f2b(v[3]);
    ((short4v*)wob)[idx] = o;
    return;
  }
  int m = blk;
  int head = t >> 3, oct = t & 7;
  int vb = head * 128 + oct * 16;
  const unsigned short* yp = y + (size_t)m * 4096 + vb;
  float yy[16];
  short8 y0 = *(const short8*)yp, y1 = *(const short8*)(yp + 8);
#pragma unroll
  for (int e = 0; e < 8; e++) { yy[e] = b2f((unsigned short)y0[e]); yy[8 + e] = b2f((unsigned short)y1[e]); }
  float ss = 0.f;
#pragma unroll
  for (int e = 0; e < 16; e++) ss += yy[e] * yy[e];
  ss += __shfl_xor(ss, 1); ss += __shfl_xor(ss, 2); ss += __shfl_xor(ss, 4);
  float rinv = rsqrtf(ss * (1.f / 128.f) + 1e-6f);
  const unsigned short* zp = qkvz + (size_t)m * NP + 8192 + vb;
  short8 z0 = *(const short8*)zp, z1 = *(const short8*)(zp + 8);
  short8 o0, o1;
#pragma unroll
  for (int e = 0; e < 8; e++) {
    float z = b2f((unsigned short)z0[e]);
    float v = nw[oct * 16 + e] * yy[e] * rinv * (z / (1.f + expf(-z)));
    o0[e] = (short)f2b(v);
    z = b2f((unsigned short)z1[e]);
    v = nw[oct * 16 + 8 + e] * yy[8 + e] * rinv * (z / (1.f + expf(-z)));
    o1[e] = (short)f2b(v);
  }
  unsigned short* op = yn + (size_t)m * 4096 + vb;
  *(short8*)op = o0;
  *(short8*)(op + 8) = o1;
}

extern "C" void kernel_launch(void* const* d_in, const int* in_sizes, int n_in,
                              void* d_out, int out_size, void* d_ws, size_t ws_size,
                              hipStream_t stream) {
  if (ws_size < WS_NEED) return;  // guard

  const float* x     = (const float*)d_in[0];
  const float* Wqkv  = (const float*)d_in[1];
  const float* Wz    = (const float*)d_in[2];
  const float* Wa    = (const float*)d_in[3];
  const float* Wb    = (const float*)d_in[4];
  const float* convw = (const float*)d_in[5];
  const float* Alog  = (const float*)d_in[6];
  const float* dtb   = (const float*)d_in[7];
  const float* nw    = (const float*)d_in[8];
  const float* Wout  = (const float*)d_in[9];

  char* ws = (char*)d_ws;
  unsigned short* qkvz = (unsigned short*)(ws + OFF_QKVZ);
  unsigned short* xb   = (unsigned short*)(ws + OFF_XB);
  unsigned short* wcat = (unsigned short*)(ws + OFF_WCAT);
  unsigned short* qkvs = (unsigned short*)(ws + OFF_QKVS);
  unsigned short* ynb  = (unsigned short*)(ws + OFF_YN);
  unsigned short* wob  = (unsigned short*)(ws + OFF_WOB);
  float* gbuf          = (float*)(ws + OFF_G);
  float* bbuf          = (float*)(ws + OFF_BET);

  float* outp       = (float*)d_out;
  float* conv_state = outp + 8388608;             // B*S*H
  float* state      = outp + 8388608 + 131072;    // + B*CI*KW
  unsigned short* ybuf = (unsigned short*)d_out;  // y bf16 scratch over outp region

  prep_all<<<33280, 256, 0, stream>>>(x, Wqkv, Wz, Wa, Wb, xb, wcat);

  gemm_db<true, unsigned short><<<1568, 512, 0, stream>>>(xb, wcat, qkvz, 2048, 32, 49, NP);

  conv_fused<<<256, 1024, 0, stream>>>(qkvz, convw, Alog, dtb, qkvs, gbuf, bbuf, conv_state);

  scan_chunk<<<256, 256, 0, stream>>>(qkvs, gbuf, bbuf, ybuf, state);

  rms_wcast<<<12288, 256, 0, stream>>>(ybuf, qkvz, nw, ynb, Wout, wob);

  gemm_db<false, float><<<256, 512, 0, stream>>>(ynb, wob, outp, 4096, 32, 8, 2048);
}